// Round 11
// baseline (768.648 us; speedup 1.0000x reference)
//
#include <hip/hip_runtime.h>

#define BATCH 8
#define NPTS 4096
#define TOTQ (BATCH * NPTS)
#define TPB 256
#define GRID 32
#define NCELLS (GRID * GRID * GRID)
#define RADF 5.5f
#define CSF 0.34375f            // 11/32, exact binary
#define INVCS (32.0f / 11.0f)
#define BIGD 1e30f

// Same key formula as validated rounds: k = w_m - 2*dot = d^2 - |p_n|^2.
__device__ __forceinline__ float cand_w(float x, float y, float z) {
    return fmaf(x, x, fmaf(y, y, z * z));
}

__device__ __forceinline__ void cell_of(float x, float y, float z,
                                        int& cx, int& cy, int& cz) {
    cx = min(max((int)floorf((x + RADF) * INVCS), 0), GRID - 1);
    cy = min(max((int)floorf((y + RADF) * INVCS), 0), GRID - 1);
    cz = min(max((int)floorf((z + RADF) * INVCS), 0), GRID - 1);
}

// ---------------- binning ----------------
__global__ __launch_bounds__(TPB) void zero_counts(uint4* p) {
    p[blockIdx.x * TPB + threadIdx.x] = make_uint4(0u, 0u, 0u, 0u);
}

__global__ __launch_bounds__(TPB) void count_cells(const float* __restrict__ coords,
                                                   unsigned* __restrict__ cellCount) {
    const int gid = blockIdx.x * TPB + (int)threadIdx.x;   // 0..TOTQ-1
    const int b = gid >> 12;
    const int n = gid & (NPTS - 1);
    const float* p = coords + ((size_t)b * NPTS + n) * 3;
    int cx, cy, cz;
    cell_of(p[0], p[1], p[2], cx, cy, cz);
    const int cidx = (cz * GRID + cy) * GRID + cx;
    atomicAdd(&cellCount[(size_t)b * NCELLS + cidx], 1u);
}

// One block per batch: exclusive prefix sum over 32768 cell counts.
__global__ __launch_bounds__(1024) void scan_cells(const unsigned* __restrict__ cellCount,
                                                   unsigned* __restrict__ cellStart,
                                                   unsigned* __restrict__ cellNext) {
    __shared__ unsigned ps[1024];
    const int b = blockIdx.x;
    const int t = (int)threadIdx.x;
    const size_t base = (size_t)b * NCELLS;
    unsigned cnt[32];
    unsigned s = 0;
#pragma unroll
    for (int i = 0; i < 32; ++i) cnt[i] = cellCount[base + t * 32 + i];
#pragma unroll
    for (int i = 0; i < 32; ++i) { unsigned tmp = cnt[i]; cnt[i] = s; s += tmp; }
    ps[t] = s;
    __syncthreads();
    for (int off = 1; off < 1024; off <<= 1) {
        unsigned add = (t >= off) ? ps[t - off] : 0u;
        __syncthreads();
        ps[t] += add;
        __syncthreads();
    }
    const unsigned tbase = ps[t] - s;   // exclusive over threads
#pragma unroll
    for (int i = 0; i < 32; ++i) {
        unsigned v = tbase + cnt[i];
        cellStart[base + t * 32 + i] = v;
        cellNext[base + t * 32 + i]  = v;
    }
}

__global__ __launch_bounds__(TPB) void scatter_points(const float* __restrict__ coords,
                                                      unsigned* __restrict__ cellNext,
                                                      float4* __restrict__ sPts,
                                                      int* __restrict__ sIdx) {
    const int gid = blockIdx.x * TPB + (int)threadIdx.x;
    const int b = gid >> 12;
    const int n = gid & (NPTS - 1);
    const float* p = coords + ((size_t)b * NPTS + n) * 3;
    const float x = p[0], y = p[1], z = p[2];
    int cx, cy, cz;
    cell_of(x, y, z, cx, cy, cz);
    const int cidx = (cz * GRID + cy) * GRID + cx;
    const unsigned pos = atomicAdd(&cellNext[(size_t)b * NCELLS + cidx], 1u);
    sPts[(size_t)b * NPTS + pos] = make_float4(-2.0f * x, -2.0f * y, -2.0f * z,
                                               cand_w(x, y, z));
    sIdx[(size_t)b * NPTS + pos] = n;
}

// ---------------- query ----------------
// One thread per SORTED slot (wave-coherent neighborhoods). Expanding
// Chebyshev shells; stop when (r-1)*cs (minus out-of-box error) exceeds the
// current 2nd-best distance (+margin). If the bound never fires, r covers the
// whole grid -> exact brute-force equivalence. Lexicographic (key, index)
// top-2 == jax stable top_k; order-independent, so scatter order is harmless.
__global__ __launch_bounds__(TPB) void knn_query(const float* __restrict__ coords,
                                                 const unsigned* __restrict__ cellStart,
                                                 const unsigned* __restrict__ cellCount,
                                                 const float4* __restrict__ sPts,
                                                 const int* __restrict__ sIdx,
                                                 float* __restrict__ out) {
    const int b = blockIdx.y;
    const int t = blockIdx.x * TPB + (int)threadIdx.x;   // sorted slot in batch
    const size_t pb = (size_t)b * NPTS;
    const size_t cb = (size_t)b * NCELLS;

    const float4 sp = sPts[pb + t];
    const float xq = -0.5f * sp.x;   // exact: recovers original coord bits
    const float yq = -0.5f * sp.y;
    const float zq = -0.5f * sp.z;
    const float sqn = sp.w;
    const int n = sIdx[pb + t];

    int cx, cy, cz;
    cell_of(xq, yq, zq, cx, cy, cz);

    // Out-of-box error (0 for all points inside [-R,R]^3).
    const float ex = fmaxf(fabsf(xq) - RADF, 0.0f);
    const float ey = fmaxf(fabsf(yq) - RADF, 0.0f);
    const float ez = fmaxf(fabsf(zq) - RADF, 0.0f);
    const float err = sqrtf(ex * ex + ey * ey + ez * ez);

    float b1k = BIGD, b2k = BIGD;
    int b1i = 0x7fffffff, b2i = 0x7fffffff;
    float d2b2 = BIGD;

    for (int r = 0; r < GRID; ++r) {
        if (r >= 1) {
            const float g = (float)(r - 1) * CSF - err;
            if (g > 0.0f && g * g > d2b2 * 1.0001f + 1e-4f) break;
        }
        const int zlo = max(cz - r, 0), zhi = min(cz + r, GRID - 1);
        for (int z = zlo; z <= zhi; ++z) {
            const int adz = (z > cz) ? (z - cz) : (cz - z);
            const int ylo = max(cy - r, 0), yhi = min(cy + r, GRID - 1);
            for (int y = ylo; y <= yhi; ++y) {
                const int ady = (y > cy) ? (y - cy) : (cy - y);
                const bool fullx = (adz == r) || (ady == r);
                const int xlo = max(cx - r, 0), xhi = min(cx + r, GRID - 1);
                for (int x = xlo; x <= xhi; ++x) {
                    if (!fullx) {
                        const int adx = (x > cx) ? (x - cx) : (cx - x);
                        if (adx != r) continue;   // interior already done
                    }
                    const int cidx = (z * GRID + y) * GRID + x;
                    const unsigned st = cellStart[cb + cidx];
                    const unsigned en = st + cellCount[cb + cidx];
                    for (unsigned s = st; s < en; ++s) {
                        if ((int)s == t) continue;   // self
                        const float4 c = sPts[pb + s];
                        const float k = fmaf(c.x, xq, fmaf(c.y, yq, fmaf(c.z, zq, c.w)));
                        const int mi = sIdx[pb + s];
                        const bool c1 = (k < b1k) || (k == b1k && mi < b1i);
                        const bool c2 = (k < b2k) || (k == b2k && mi < b2i);
                        const float nb2 = c1 ? b1k : (c2 ? k : b2k);
                        const int   ni2 = c1 ? b1i : (c2 ? mi : b2i);
                        b1k = c1 ? k : b1k;
                        b1i = c1 ? mi : b1i;
                        b2k = nb2;
                        b2i = ni2;
                    }
                }
            }
        }
        d2b2 = b2k + sqn;   // translate key back to d^2 bound
    }

    const float* basep = coords + pb * 3;
    const int q = b * NPTS + n;
    float* A  = out;
    float* C  = out + (size_t)TOTQ * 3;
    float* I1 = out + (size_t)2 * TOTQ * 3;
    float* I2 = I1 + (size_t)TOTQ;

    A[(size_t)q * 3 + 0] = basep[b1i * 3 + 0];
    A[(size_t)q * 3 + 1] = basep[b1i * 3 + 1];
    A[(size_t)q * 3 + 2] = basep[b1i * 3 + 2];
    C[(size_t)q * 3 + 0] = basep[b2i * 3 + 0];
    C[(size_t)q * 3 + 1] = basep[b2i * 3 + 1];
    C[(size_t)q * 3 + 2] = basep[b2i * 3 + 2];
    I1[q] = (float)b1i;
    I2[q] = (float)b2i;
}

// ---------------- fallback (tiny ws): monolithic brute force ----------------
__device__ __forceinline__ void top2min(float k, int m,
                                        float& b1, int& i1,
                                        float& b2, int& i2) {
    bool c1 = k < b1;
    bool c2 = k < b2;
    int ni2 = c2 ? m : i2;
    i2 = c1 ? i1 : ni2;
    i1 = c1 ? m : i1;
    b2 = fminf(fmaxf(k, b1), b2);
    b1 = fminf(k, b1);
}

__global__ __launch_bounds__(TPB) void knn_full(const float* __restrict__ coords,
                                                float* __restrict__ out) {
    __shared__ float4 pts[NPTS];  // 64 KB
    const int tid  = (int)threadIdx.x;
    const int tile = blockIdx.x;
    const int b    = blockIdx.y;
    const float* basep = coords + (size_t)b * NPTS * 3;

    for (int p = tid; p < NPTS; p += TPB) {
        float x = basep[p * 3 + 0];
        float y = basep[p * 3 + 1];
        float z = basep[p * 3 + 2];
        pts[p] = make_float4(-2.0f * x, -2.0f * y, -2.0f * z, cand_w(x, y, z));
    }
    const int n = tile * TPB + tid;
    const float xn = basep[n * 3 + 0];
    const float yn = basep[n * 3 + 1];
    const float zn = basep[n * 3 + 2];
    __syncthreads();

    float b1 = BIGD, b2 = BIGD;
    int i1 = 0, i2 = 0;
    for (int p = 0; p < NPTS; p += 4) {
#pragma unroll
        for (int j = 0; j < 4; ++j) {
            float4 c = pts[p + j];
            float k = fmaf(c.x, xn, fmaf(c.y, yn, fmaf(c.z, zn, c.w)));
            k = (p + j == n) ? BIGD : k;
            top2min(k, p + j, b1, i1, b2, i2);
        }
    }

    const int q = b * NPTS + n;
    float* A  = out;
    float* C  = out + (size_t)TOTQ * 3;
    float* I1 = out + (size_t)2 * TOTQ * 3;
    float* I2 = I1 + (size_t)TOTQ;
    float4 p1 = pts[i1];
    float4 p2 = pts[i2];
    A[(size_t)q * 3 + 0] = -0.5f * p1.x;
    A[(size_t)q * 3 + 1] = -0.5f * p1.y;
    A[(size_t)q * 3 + 2] = -0.5f * p1.z;
    C[(size_t)q * 3 + 0] = -0.5f * p2.x;
    C[(size_t)q * 3 + 1] = -0.5f * p2.y;
    C[(size_t)q * 3 + 2] = -0.5f * p2.z;
    I1[q] = (float)i1;
    I2[q] = (float)i2;
}

extern "C" void kernel_launch(void* const* d_in, const int* in_sizes, int n_in,
                              void* d_out, int out_size, void* d_ws, size_t ws_size,
                              hipStream_t stream) {
    const float* coords = (const float*)d_in[0];
    float* out = (float*)d_out;

    // ws layout: cellCount 1MB | cellStart 1MB | cellNext 1MB | sPts 512KB | sIdx 128KB
    const size_t MB = 1u << 20;
    if (ws_size >= 4 * MB) {
        unsigned char* w = (unsigned char*)d_ws;
        unsigned* cellCount = (unsigned*)(w);
        unsigned* cellStart = (unsigned*)(w + 1 * MB);
        unsigned* cellNext  = (unsigned*)(w + 2 * MB);
        float4*   sPts      = (float4*)(w + 3 * MB);
        int*      sIdx      = (int*)(w + 3 * MB + 512 * 1024);

        // zero cellCount: 8*32768 u32 = 65536 uint4
        hipLaunchKernelGGL(zero_counts, dim3(65536 / TPB), dim3(TPB), 0, stream,
                           (uint4*)cellCount);
        hipLaunchKernelGGL(count_cells, dim3(TOTQ / TPB), dim3(TPB), 0, stream,
                           coords, cellCount);
        hipLaunchKernelGGL(scan_cells, dim3(BATCH), dim3(1024), 0, stream,
                           cellCount, cellStart, cellNext);
        hipLaunchKernelGGL(scatter_points, dim3(TOTQ / TPB), dim3(TPB), 0, stream,
                           coords, cellNext, sPts, sIdx);
        hipLaunchKernelGGL(knn_query, dim3(NPTS / TPB, BATCH), dim3(TPB), 0, stream,
                           coords, cellStart, cellCount, sPts, sIdx, out);
    } else {
        hipLaunchKernelGGL(knn_full, dim3(NPTS / TPB, BATCH), dim3(TPB), 0, stream,
                           coords, out);
    }
}

// Round 12
// 133.032 us; speedup vs baseline: 5.7779x; 5.7779x over previous
//
#include <hip/hip_runtime.h>

#define BATCH 8
#define NPTS 4096
#define TOTQ (BATCH * NPTS)
#define TPB 256
#define GRIDC 32
#define NCELLS (GRIDC * GRIDC * GRIDC)
#define RADF 5.5f
#define CSF 0.34375f            // 11/32, exact binary
#define INVCS (32.0f / 11.0f)
#define BIGD 1e30f
#define MAXI 0x7fffffff

// ---- key formula (validated bitwise vs reference in R1-R11, absmax 0) ----
__device__ __forceinline__ float cand_w(float x, float y, float z) {
    return fmaf(x, x, fmaf(y, y, z * z));
}

__device__ __forceinline__ void cell_of(float x, float y, float z,
                                        int& cx, int& cy, int& cz) {
    cx = min(max((int)floorf((x + RADF) * INVCS), 0), GRIDC - 1);
    cy = min(max((int)floorf((y + RADF) * INVCS), 0), GRIDC - 1);
    cz = min(max((int)floorf((z + RADF) * INVCS), 0), GRIDC - 1);
}

// Lexicographic (key, index) top-2 — order-independent, == jax stable top_k.
__device__ __forceinline__ void lexup(float k, int i,
                                      float& b1, int& i1,
                                      float& b2, int& i2) {
    bool c1 = (k < b1) || (k == b1 && i < i1);
    bool c2 = (k < b2) || (k == b2 && i < i2);
    float nb2 = c1 ? b1 : (c2 ? k : b2);
    int   ni2 = c1 ? i1 : (c2 ? i : i2);
    b1 = c1 ? k : b1;
    i1 = c1 ? i : i1;
    b2 = nb2;
    i2 = ni2;
}

// ---------------- binning (validated in R11) ----------------
__global__ __launch_bounds__(TPB) void zero_counts(uint4* p, unsigned* failCount) {
    p[blockIdx.x * TPB + threadIdx.x] = make_uint4(0u, 0u, 0u, 0u);
    if (blockIdx.x == 0 && threadIdx.x == 0) *failCount = 0u;
}

__global__ __launch_bounds__(TPB) void count_cells(const float* __restrict__ coords,
                                                   unsigned* __restrict__ cellCount) {
    const int gid = blockIdx.x * TPB + (int)threadIdx.x;
    const int b = gid >> 12;
    const int n = gid & (NPTS - 1);
    const float* p = coords + ((size_t)b * NPTS + n) * 3;
    int cx, cy, cz;
    cell_of(p[0], p[1], p[2], cx, cy, cz);
    atomicAdd(&cellCount[(size_t)b * NCELLS + (cz * GRIDC + cy) * GRIDC + cx], 1u);
}

__global__ __launch_bounds__(1024) void scan_cells(const unsigned* __restrict__ cellCount,
                                                   unsigned* __restrict__ cellStart,
                                                   unsigned* __restrict__ cellNext) {
    __shared__ unsigned ps[1024];
    const int b = blockIdx.x;
    const int t = (int)threadIdx.x;
    const size_t base = (size_t)b * NCELLS;
    unsigned cnt[32];
    unsigned s = 0;
#pragma unroll
    for (int i = 0; i < 32; ++i) cnt[i] = cellCount[base + t * 32 + i];
#pragma unroll
    for (int i = 0; i < 32; ++i) { unsigned tmp = cnt[i]; cnt[i] = s; s += tmp; }
    ps[t] = s;
    __syncthreads();
    for (int off = 1; off < 1024; off <<= 1) {
        unsigned add = (t >= off) ? ps[t - off] : 0u;
        __syncthreads();
        ps[t] += add;
        __syncthreads();
    }
    const unsigned tbase = ps[t] - s;
#pragma unroll
    for (int i = 0; i < 32; ++i) {
        unsigned v = tbase + cnt[i];
        cellStart[base + t * 32 + i] = v;
        cellNext[base + t * 32 + i]  = v;
    }
}

__global__ __launch_bounds__(TPB) void scatter_points(const float* __restrict__ coords,
                                                      unsigned* __restrict__ cellNext,
                                                      float4* __restrict__ sPts,
                                                      int* __restrict__ sIdx) {
    const int gid = blockIdx.x * TPB + (int)threadIdx.x;
    const int b = gid >> 12;
    const int n = gid & (NPTS - 1);
    const float* p = coords + ((size_t)b * NPTS + n) * 3;
    const float x = p[0], y = p[1], z = p[2];
    int cx, cy, cz;
    cell_of(x, y, z, cx, cy, cz);
    const unsigned pos = atomicAdd(&cellNext[(size_t)b * NCELLS + (cz * GRIDC + cy) * GRIDC + cx], 1u);
    sPts[(size_t)b * NPTS + pos] = make_float4(-2.0f * x, -2.0f * y, -2.0f * z,
                                               cand_w(x, y, z));
    sIdx[(size_t)b * NPTS + pos] = n;
}

// ---------------- phase A: fixed 3^3 scan + exactness certificate ----------------
// block = 64 queries (consecutive sorted slots) x 4 cell-subsets (1 wave each).
// Coverage: every point within L-inf radius R (q to its 3^3-block boundary) is
// scanned; clamped edge cells only ever contain points FARTHER than the face.
// pass iff d2nd < R*(1-eps)  ->  found top-2 is globally exact.
__global__ __launch_bounds__(TPB) void phaseA(const float* __restrict__ coords,
                                              const unsigned* __restrict__ cellStart,
                                              const unsigned* __restrict__ cellCount,
                                              const float4* __restrict__ sPts,
                                              const int* __restrict__ sIdx,
                                              int* __restrict__ failList,
                                              unsigned* __restrict__ failCount,
                                              float* __restrict__ out) {
    __shared__ float4 part[TPB];
    const int t   = (int)threadIdx.x;
    const int sub = t >> 6;          // wave id 0..3
    const int qi  = t & 63;
    const int b   = blockIdx.y;
    const int slot = blockIdx.x * 64 + qi;
    const size_t pb = (size_t)b * NPTS;
    const size_t cb = (size_t)b * NCELLS;

    const float4 sp = sPts[pb + slot];
    const float xq = -0.5f * sp.x;   // exact bit-recovery of the coordinate
    const float yq = -0.5f * sp.y;
    const float zq = -0.5f * sp.z;
    const float sqn = sp.w;
    int cx, cy, cz;
    cell_of(xq, yq, zq, cx, cy, cz);

    float b1 = BIGD, b2 = BIGD;
    int i1 = MAXI, i2 = MAXI;
    for (int g = sub; g < 27; g += 4) {
        const int z = cz + (g / 9) - 1;
        const int y = cy + ((g / 3) % 3) - 1;
        const int x = cx + (g % 3) - 1;
        if ((unsigned)z > (GRIDC - 1u) || (unsigned)y > (GRIDC - 1u) ||
            (unsigned)x > (GRIDC - 1u)) continue;
        const int cidx = (z * GRIDC + y) * GRIDC + x;
        const unsigned st = cellStart[cb + cidx];
        const unsigned en = st + cellCount[cb + cidx];
        for (unsigned s = st; s < en; ++s) {
            if ((int)s == slot) continue;
            const float4 c = sPts[pb + s];
            const int mi = sIdx[pb + s];
            const float k = fmaf(c.x, xq, fmaf(c.y, yq, fmaf(c.z, zq, c.w)));
            lexup(k, mi, b1, i1, b2, i2);
        }
    }
    part[sub * 64 + qi] = make_float4(b1, __int_as_float(i1), b2, __int_as_float(i2));
    __syncthreads();

    if (sub == 0) {
#pragma unroll
        for (int ss = 1; ss < 4; ++ss) {
            const float4 p = part[ss * 64 + qi];
            lexup(p.x, __float_as_int(p.y), b1, i1, b2, i2);
            lexup(p.z, __float_as_int(p.w), b1, i1, b2, i2);
        }
        // certificate
        const float lox = (float)(max(cx - 1, 0)) * CSF - RADF;
        const float hix = (float)(min(cx + 1, GRIDC - 1) + 1) * CSF - RADF;
        const float loy = (float)(max(cy - 1, 0)) * CSF - RADF;
        const float hiy = (float)(min(cy + 1, GRIDC - 1) + 1) * CSF - RADF;
        const float loz = (float)(max(cz - 1, 0)) * CSF - RADF;
        const float hiz = (float)(min(cz + 1, GRIDC - 1) + 1) * CSF - RADF;
        float R = fminf(fminf(xq - lox, hix - xq),
                  fminf(fminf(yq - loy, hiy - yq),
                        fminf(zq - loz, hiz - zq)));
        const float Rm = R * 0.999f - 1e-4f;
        const float d2 = b2 + sqn;   // back to distance^2 (abs err ~1e-6 << margin)
        const bool pass = (b2 < 0.5f * BIGD) && (Rm > 0.0f) && (d2 < Rm * Rm);
        const int n = sIdx[pb + slot];
        if (pass) {
            const float* basep = coords + pb * 3;
            const int q = b * NPTS + n;
            float* A  = out;
            float* C  = out + (size_t)TOTQ * 3;
            float* I1 = out + (size_t)2 * TOTQ * 3;
            float* I2 = I1 + (size_t)TOTQ;
            A[(size_t)q * 3 + 0] = basep[i1 * 3 + 0];
            A[(size_t)q * 3 + 1] = basep[i1 * 3 + 1];
            A[(size_t)q * 3 + 2] = basep[i1 * 3 + 2];
            C[(size_t)q * 3 + 0] = basep[i2 * 3 + 0];
            C[(size_t)q * 3 + 1] = basep[i2 * 3 + 1];
            C[(size_t)q * 3 + 2] = basep[i2 * 3 + 2];
            I1[q] = (float)i1;
            I2[q] = (float)i2;
        } else {
            const unsigned pos = atomicAdd(failCount, 1u);
            failList[pos] = (b << 12) | slot;
        }
    }
}

// ---------------- phase B: exact brute force, one WAVE per failed query ----
// 64 lanes split 4096 candidates (coalesced float4 from L2-resident sPts),
// lexicographic top-2 per lane, 6-step shuffle butterfly merge.
__global__ __launch_bounds__(TPB) void phaseB(const float* __restrict__ coords,
                                              const float4* __restrict__ sPts,
                                              const int* __restrict__ sIdx,
                                              const int* __restrict__ failList,
                                              const unsigned* __restrict__ failCount,
                                              float* __restrict__ out) {
    const int lane = (int)threadIdx.x & 63;
    const int w = blockIdx.x * (TPB / 64) + ((int)threadIdx.x >> 6);
    const int NW = gridDim.x * (TPB / 64);
    const unsigned fc = *failCount;

    for (unsigned f = w; f < fc; f += NW) {
        const int e = failList[f];
        const int b = e >> 12;
        const int slot = e & (NPTS - 1);
        const size_t pb = (size_t)b * NPTS;
        const float4 sp = sPts[pb + slot];
        const float xq = -0.5f * sp.x;
        const float yq = -0.5f * sp.y;
        const float zq = -0.5f * sp.z;
        const int n = sIdx[pb + slot];

        float b1 = BIGD, b2 = BIGD;
        int i1 = MAXI, i2 = MAXI;
        for (int s = lane; s < NPTS; s += 64) {
            if (s == slot) continue;
            const float4 c = sPts[pb + s];
            const int mi = sIdx[pb + s];
            const float k = fmaf(c.x, xq, fmaf(c.y, yq, fmaf(c.z, zq, c.w)));
            lexup(k, mi, b1, i1, b2, i2);
        }
#pragma unroll
        for (int off = 1; off < 64; off <<= 1) {
            const float ok1 = __shfl_xor(b1, off);
            const int   oi1 = __shfl_xor(i1, off);
            const float ok2 = __shfl_xor(b2, off);
            const int   oi2 = __shfl_xor(i2, off);
            lexup(ok1, oi1, b1, i1, b2, i2);
            lexup(ok2, oi2, b1, i1, b2, i2);
        }
        if (lane == 0) {
            const float* basep = coords + pb * 3;
            const int q = b * NPTS + n;
            float* A  = out;
            float* C  = out + (size_t)TOTQ * 3;
            float* I1 = out + (size_t)2 * TOTQ * 3;
            float* I2 = I1 + (size_t)TOTQ;
            A[(size_t)q * 3 + 0] = basep[i1 * 3 + 0];
            A[(size_t)q * 3 + 1] = basep[i1 * 3 + 1];
            A[(size_t)q * 3 + 2] = basep[i1 * 3 + 2];
            C[(size_t)q * 3 + 0] = basep[i2 * 3 + 0];
            C[(size_t)q * 3 + 1] = basep[i2 * 3 + 1];
            C[(size_t)q * 3 + 2] = basep[i2 * 3 + 2];
            I1[q] = (float)i1;
            I2[q] = (float)i2;
        }
    }
}

// ---------------- fallback (tiny ws): monolithic brute force ----------------
__device__ __forceinline__ void top2min(float k, int m,
                                        float& b1, int& i1,
                                        float& b2, int& i2) {
    bool c1 = k < b1;
    bool c2 = k < b2;
    int ni2 = c2 ? m : i2;
    i2 = c1 ? i1 : ni2;
    i1 = c1 ? m : i1;
    b2 = fminf(fmaxf(k, b1), b2);
    b1 = fminf(k, b1);
}

__global__ __launch_bounds__(TPB) void knn_full(const float* __restrict__ coords,
                                                float* __restrict__ out) {
    __shared__ float4 pts[NPTS];  // 64 KB
    const int tid  = (int)threadIdx.x;
    const int tile = blockIdx.x;
    const int b    = blockIdx.y;
    const float* basep = coords + (size_t)b * NPTS * 3;

    for (int p = tid; p < NPTS; p += TPB) {
        float x = basep[p * 3 + 0];
        float y = basep[p * 3 + 1];
        float z = basep[p * 3 + 2];
        pts[p] = make_float4(-2.0f * x, -2.0f * y, -2.0f * z, cand_w(x, y, z));
    }
    const int n = tile * TPB + tid;
    const float xn = basep[n * 3 + 0];
    const float yn = basep[n * 3 + 1];
    const float zn = basep[n * 3 + 2];
    __syncthreads();

    float b1 = BIGD, b2 = BIGD;
    int i1 = 0, i2 = 0;
    for (int p = 0; p < NPTS; p += 4) {
#pragma unroll
        for (int j = 0; j < 4; ++j) {
            float4 c = pts[p + j];
            float k = fmaf(c.x, xn, fmaf(c.y, yn, fmaf(c.z, zn, c.w)));
            k = (p + j == n) ? BIGD : k;
            top2min(k, p + j, b1, i1, b2, i2);
        }
    }

    const int q = b * NPTS + n;
    float* A  = out;
    float* C  = out + (size_t)TOTQ * 3;
    float* I1 = out + (size_t)2 * TOTQ * 3;
    float* I2 = I1 + (size_t)TOTQ;
    float4 p1 = pts[i1];
    float4 p2 = pts[i2];
    A[(size_t)q * 3 + 0] = -0.5f * p1.x;
    A[(size_t)q * 3 + 1] = -0.5f * p1.y;
    A[(size_t)q * 3 + 2] = -0.5f * p1.z;
    C[(size_t)q * 3 + 0] = -0.5f * p2.x;
    C[(size_t)q * 3 + 1] = -0.5f * p2.y;
    C[(size_t)q * 3 + 2] = -0.5f * p2.z;
    I1[q] = (float)i1;
    I2[q] = (float)i2;
}

extern "C" void kernel_launch(void* const* d_in, const int* in_sizes, int n_in,
                              void* d_out, int out_size, void* d_ws, size_t ws_size,
                              hipStream_t stream) {
    const float* coords = (const float*)d_in[0];
    float* out = (float*)d_out;

    const size_t MB = 1u << 20;
    if (ws_size >= 4 * MB) {
        unsigned char* w = (unsigned char*)d_ws;
        unsigned* cellCount = (unsigned*)(w);                       // 1 MB
        unsigned* cellStart = (unsigned*)(w + 1 * MB);              // 1 MB
        unsigned* cellNext  = (unsigned*)(w + 2 * MB);              // 1 MB
        float4*   sPts      = (float4*)(w + 3 * MB);                // 512 KB
        int*      sIdx      = (int*)(w + 3 * MB + 512 * 1024);      // 128 KB
        int*      failList  = (int*)(w + 3 * MB + 640 * 1024);      // 128 KB
        unsigned* failCount = (unsigned*)(w + 3 * MB + 768 * 1024); // 4 B

        hipLaunchKernelGGL(zero_counts, dim3(65536 / TPB), dim3(TPB), 0, stream,
                           (uint4*)cellCount, failCount);
        hipLaunchKernelGGL(count_cells, dim3(TOTQ / TPB), dim3(TPB), 0, stream,
                           coords, cellCount);
        hipLaunchKernelGGL(scan_cells, dim3(BATCH), dim3(1024), 0, stream,
                           cellCount, cellStart, cellNext);
        hipLaunchKernelGGL(scatter_points, dim3(TOTQ / TPB), dim3(TPB), 0, stream,
                           coords, cellNext, sPts, sIdx);
        hipLaunchKernelGGL(phaseA, dim3(NPTS / 64, BATCH), dim3(TPB), 0, stream,
                           coords, cellStart, cellCount, sPts, sIdx,
                           failList, failCount, out);
        hipLaunchKernelGGL(phaseB, dim3(2048), dim3(TPB), 0, stream,
                           coords, sPts, sIdx, failList, failCount, out);
    } else {
        hipLaunchKernelGGL(knn_full, dim3(NPTS / TPB, BATCH), dim3(TPB), 0, stream,
                           coords, out);
    }
}

// Round 13
// 123.853 us; speedup vs baseline: 6.2061x; 1.0741x over previous
//
#include <hip/hip_runtime.h>

#define BATCH 8
#define NPTS 4096
#define TOTQ (BATCH * NPTS)
#define TPB 256
#define NCH 64            // chunks per batch
#define CSZ 64            // NPTS/NCH = points per chunk = wave size
#define QF 8              // queries per thread in scan
#define BIGD 1e30f
#define MAXI 0x7fffffff

// ---- key formula: bitwise identical everywhere (validated R1-R12) ----
// candidate m as (-2x,-2y,-2z,w=x^2+y^2+z^2); key = w - 2*dot = d^2 - |pn|^2
__device__ __forceinline__ float cand_w(float x, float y, float z) {
    return fmaf(x, x, fmaf(y, y, z * z));
}
__device__ __forceinline__ float cand_key(float cx, float cy, float cz, float w,
                                          float xn, float yn, float zn) {
    return fmaf(cx, xn, fmaf(cy, yn, fmaf(cz, zn, w)));
}

// Lexicographic (key, index) top-2: order-independent, == jax stable top_k.
__device__ __forceinline__ void lexup(float k, int i,
                                      float& b1, int& i1,
                                      float& b2, int& i2) {
    bool c1 = (k < b1) || (k == b1 && i < i1);
    bool c2 = (k < b2) || (k == b2 && i < i2);
    float nb2 = c1 ? b1 : (c2 ? k : b2);
    int   ni2 = c1 ? i1 : (c2 ? i : i2);
    b1 = c1 ? k : b1;
    i1 = c1 ? i : i1;
    b2 = nb2;
    i2 = ni2;
}

// ---------------- pass 1: value-only scan (5 VALU/pair, no select chains) ---
// block = (query tile of TPB*QF, chunk, batch). Self candidate included (its
// key is the strict chunk min); merge skips the self chunk's values entirely.
__global__ __launch_bounds__(TPB) void knn_scan_v(const float* __restrict__ coords,
                                                  float2* __restrict__ vals) {
    __shared__ float4 pts[CSZ];
    const int tid   = (int)threadIdx.x;
    const int tile  = blockIdx.x;
    const int chunk = blockIdx.y;
    const int b     = blockIdx.z;
    const float* basep = coords + (size_t)b * NPTS * 3;
    const int mbase = chunk * CSZ;

    if (tid < CSZ) {
        float x = basep[(mbase + tid) * 3 + 0];
        float y = basep[(mbase + tid) * 3 + 1];
        float z = basep[(mbase + tid) * 3 + 2];
        pts[tid] = make_float4(-2.0f * x, -2.0f * y, -2.0f * z, cand_w(x, y, z));
    }

    const int qbase = tile * (TPB * QF);
    float xn[QF], yn[QF], zn[QF], b1[QF], b2[QF];
#pragma unroll
    for (int q = 0; q < QF; ++q) {
        int n = qbase + q * TPB + tid;
        xn[q] = basep[n * 3 + 0];
        yn[q] = basep[n * 3 + 1];
        zn[q] = basep[n * 3 + 2];
        b1[q] = BIGD; b2[q] = BIGD;
    }
    __syncthreads();

    for (int p = 0; p < CSZ; p += 4) {
        float4 c[4];
#pragma unroll
        for (int j = 0; j < 4; ++j) c[j] = pts[p + j];
#pragma unroll
        for (int j = 0; j < 4; ++j) {
#pragma unroll
            for (int q = 0; q < QF; ++q) {
                float k = cand_key(c[j].x, c[j].y, c[j].z, c[j].w, xn[q], yn[q], zn[q]);
                b2[q] = fminf(fmaxf(k, b1[q]), b2[q]);   // med3 given b1<=b2
                b1[q] = fminf(k, b1[q]);
            }
        }
    }

#pragma unroll
    for (int q = 0; q < QF; ++q) {
        int n = qbase + q * TPB + tid;
        vals[(size_t)chunk * TOTQ + (size_t)b * NPTS + n] = make_float2(b1[q], b2[q]);
    }
}

// ---------------- pass 2: tagged value merge + wave-cooperative rescan ------
// Block = 64 queries (one batch, 64-aligned -> c_self block-uniform).
// Phase 1 (per-thread, 4 subsets/query): tagged top-2 over non-self chunks.
// Phase 2: rescan set = sorted {c_self, ca, cb} (coverage proven: any true
// 1st/2nd neighbor's chunk is ca or cb or c_self, incl. all tie cases since
// chunk number is monotone in point index).
// Phase 3: one WAVE per query, lane = candidate within chunk (CSZ=64):
// coalesced coord loads, bitwise-identical keys, lexicographic butterfly.
__global__ __launch_bounds__(TPB) void knn_merge_w(const float* __restrict__ coords,
                                                   const float2* __restrict__ vals,
                                                   float* __restrict__ out) {
    __shared__ float4 part[4][CSZ];
    __shared__ int4 rl[CSZ];
    __shared__ int2 res[CSZ];
    const int t  = (int)threadIdx.x;
    const int qi = t & 63;
    const int s  = t >> 6;
    const int qb = blockIdx.x * 64;            // global query base (batch-aligned)
    const int q  = qb + qi;
    const int b  = qb >> 12;
    const int c_self = (qb & (NPTS - 1)) >> 6; // block-uniform
    const float* bp = coords + (size_t)b * NPTS * 3;

    // Phase 1: 16 chunks per thread, coalesced vals reads.
    float f1 = BIGD, f2 = BIGD;
    int t1 = MAXI, t2 = MAXI;
    for (int c = s * 16; c < s * 16 + 16; ++c) {
        if (c == c_self) continue;             // block-uniform branch
        float2 v = vals[(size_t)c * TOTQ + q];
        lexup(v.x, 2 * c + 0, f1, t1, f2, t2);
        lexup(v.y, 2 * c + 1, f1, t1, f2, t2);
    }
    part[s][qi] = make_float4(f1, __int_as_float(t1), f2, __int_as_float(t2));
    __syncthreads();

    // Phase 2: combine subsets, build sorted rescan list.
    if (s == 0) {
#pragma unroll
        for (int ss = 1; ss < 4; ++ss) {
            float4 p = part[ss][qi];
            lexup(p.x, __float_as_int(p.y), f1, t1, f2, t2);
            lexup(p.z, __float_as_int(p.w), f1, t1, f2, t2);
        }
        const int ca = t1 >> 1;
        const int cb = t2 >> 1;
        const int lo = min(min(ca, cb), c_self);
        const int hi = max(max(ca, cb), c_self);
        const int md = ca + cb + c_self - lo - hi;
        rl[qi] = make_int4(lo, md, hi, 0);
    }
    __syncthreads();

    // Phase 3: wave w handles queries w*16 .. w*16+15, all 64 lanes cooperate.
    const int lane = qi;
    const int w = s;
    for (int j = 0; j < 16; ++j) {
        const int qj = w * 16 + j;
        const int4 r = rl[qj];                 // LDS broadcast
        const int n = (qb + qj) & (NPTS - 1);
        const float xq = bp[n * 3 + 0];        // broadcast loads
        const float yq = bp[n * 3 + 1];
        const float zq = bp[n * 3 + 2];

        float b1 = BIGD, b2 = BIGD;
        int i1 = MAXI, i2 = MAXI;
        int prev = -1;
#pragma unroll
        for (int u = 0; u < 3; ++u) {
            const int c = (u == 0) ? r.x : (u == 1) ? r.y : r.z;
            if (c == prev) continue;           // dedup (wave-uniform)
            prev = c;
            const int m = c * CSZ + lane;
            const float x = bp[m * 3 + 0];     // coalesced (12B stride)
            const float y = bp[m * 3 + 1];
            const float z = bp[m * 3 + 2];
            const float wv = cand_w(x, y, z);
            float k = cand_key(-2.0f * x, -2.0f * y, -2.0f * z, wv, xq, yq, zq);
            const bool self = (m == n);
            k = self ? BIGD : k;
            lexup(k, self ? MAXI : m, b1, i1, b2, i2);
        }
        // 64-lane lexicographic butterfly top-2.
#pragma unroll
        for (int off = 1; off < 64; off <<= 1) {
            const float ok1 = __shfl_xor(b1, off);
            const int   oi1 = __shfl_xor(i1, off);
            const float ok2 = __shfl_xor(b2, off);
            const int   oi2 = __shfl_xor(i2, off);
            lexup(ok1, oi1, b1, i1, b2, i2);
            lexup(ok2, oi2, b1, i1, b2, i2);
        }
        if (lane == 0) res[qj] = make_int2(i1, i2);
    }
    __syncthreads();

    // Phase 4: parallel epilogue (threads 0-63, one query each).
    if (s == 0) {
        const int i1 = res[qi].x;
        const int i2 = res[qi].y;
        float* A  = out;
        float* C  = out + (size_t)TOTQ * 3;
        float* I1 = out + (size_t)2 * TOTQ * 3;
        float* I2 = I1 + (size_t)TOTQ;
        A[(size_t)q * 3 + 0] = bp[i1 * 3 + 0];
        A[(size_t)q * 3 + 1] = bp[i1 * 3 + 1];
        A[(size_t)q * 3 + 2] = bp[i1 * 3 + 2];
        C[(size_t)q * 3 + 0] = bp[i2 * 3 + 0];
        C[(size_t)q * 3 + 1] = bp[i2 * 3 + 1];
        C[(size_t)q * 3 + 2] = bp[i2 * 3 + 2];
        I1[q] = (float)i1;
        I2[q] = (float)i2;
    }
}

// ---------------- fallback (tiny ws): monolithic brute force ----------------
__device__ __forceinline__ void top2min(float k, int m,
                                        float& b1, int& i1,
                                        float& b2, int& i2) {
    bool c1 = k < b1;
    bool c2 = k < b2;
    int ni2 = c2 ? m : i2;
    i2 = c1 ? i1 : ni2;
    i1 = c1 ? m : i1;
    b2 = fminf(fmaxf(k, b1), b2);
    b1 = fminf(k, b1);
}

__global__ __launch_bounds__(TPB) void knn_full(const float* __restrict__ coords,
                                                float* __restrict__ out) {
    __shared__ float4 pts[NPTS];  // 64 KB
    const int tid  = (int)threadIdx.x;
    const int tile = blockIdx.x;
    const int b    = blockIdx.y;
    const float* basep = coords + (size_t)b * NPTS * 3;

    for (int p = tid; p < NPTS; p += TPB) {
        float x = basep[p * 3 + 0];
        float y = basep[p * 3 + 1];
        float z = basep[p * 3 + 2];
        pts[p] = make_float4(-2.0f * x, -2.0f * y, -2.0f * z, cand_w(x, y, z));
    }
    const int n = tile * TPB + tid;
    const float xn = basep[n * 3 + 0];
    const float yn = basep[n * 3 + 1];
    const float zn = basep[n * 3 + 2];
    __syncthreads();

    float b1 = BIGD, b2 = BIGD;
    int i1 = 0, i2 = 0;
    for (int p = 0; p < NPTS; p += 4) {
#pragma unroll
        for (int j = 0; j < 4; ++j) {
            float4 c = pts[p + j];
            float k = cand_key(c.x, c.y, c.z, c.w, xn, yn, zn);
            k = (p + j == n) ? BIGD : k;
            top2min(k, p + j, b1, i1, b2, i2);
        }
    }

    const int q = b * NPTS + n;
    float* A  = out;
    float* C  = out + (size_t)TOTQ * 3;
    float* I1 = out + (size_t)2 * TOTQ * 3;
    float* I2 = I1 + (size_t)TOTQ;
    float4 p1 = pts[i1];
    float4 p2 = pts[i2];
    A[(size_t)q * 3 + 0] = -0.5f * p1.x;
    A[(size_t)q * 3 + 1] = -0.5f * p1.y;
    A[(size_t)q * 3 + 2] = -0.5f * p1.z;
    C[(size_t)q * 3 + 0] = -0.5f * p2.x;
    C[(size_t)q * 3 + 1] = -0.5f * p2.y;
    C[(size_t)q * 3 + 2] = -0.5f * p2.z;
    I1[q] = (float)i1;
    I2[q] = (float)i2;
}

extern "C" void kernel_launch(void* const* d_in, const int* in_sizes, int n_in,
                              void* d_out, int out_size, void* d_ws, size_t ws_size,
                              hipStream_t stream) {
    const float* coords = (const float*)d_in[0];
    float* out = (float*)d_out;

    const size_t need = (size_t)NCH * TOTQ * sizeof(float2);   // 16 MB
    if (ws_size >= need) {
        float2* vals = (float2*)d_ws;
        // scan: (4096/(256*8)=2 tiles, 64 chunks, 8 batches) = 1024 blocks
        hipLaunchKernelGGL(knn_scan_v, dim3(NPTS / (TPB * QF), NCH, BATCH), dim3(TPB),
                           0, stream, coords, vals);
        // merge: 512 blocks x 256 threads (64 queries each)
        hipLaunchKernelGGL(knn_merge_w, dim3(TOTQ / 64), dim3(TPB), 0, stream,
                           coords, vals, out);
    } else {
        hipLaunchKernelGGL(knn_full, dim3(NPTS / TPB, BATCH), dim3(TPB), 0, stream,
                           coords, out);
    }
}

// Round 14
// 99.795 us; speedup vs baseline: 7.7023x; 1.2411x over previous
//
#include <hip/hip_runtime.h>

#define BATCH 8
#define NPTS 4096
#define TOTQ (BATCH * NPTS)
#define TPB 256
#define NCH 64            // chunks per batch
#define CSZ 64            // NPTS/NCH = points per chunk = wave size
#define QF 8              // queries per thread in scan
#define QPB 16            // queries per merge block
#define BIGD 1e30f
#define MAXI 0x7fffffff

// ---- key formula: bitwise identical everywhere (validated R1-R13) ----
// candidate m as (-2x,-2y,-2z,w=x^2+y^2+z^2); key = w - 2*dot = d^2 - |pn|^2
__device__ __forceinline__ float cand_w(float x, float y, float z) {
    return fmaf(x, x, fmaf(y, y, z * z));
}
__device__ __forceinline__ float cand_key(float cx, float cy, float cz, float w,
                                          float xn, float yn, float zn) {
    return fmaf(cx, xn, fmaf(cy, yn, fmaf(cz, zn, w)));
}

// Lexicographic (key, index) top-2: order-independent, == jax stable top_k.
// NOT idempotent on duplicate feeds -> duplicate chunks must be skipped.
__device__ __forceinline__ void lexup(float k, int i,
                                      float& b1, int& i1,
                                      float& b2, int& i2) {
    bool c1 = (k < b1) || (k == b1 && i < i1);
    bool c2 = (k < b2) || (k == b2 && i < i2);
    float nb2 = c1 ? b1 : (c2 ? k : b2);
    int   ni2 = c1 ? i1 : (c2 ? i : i2);
    b1 = c1 ? k : b1;
    i1 = c1 ? i : i1;
    b2 = nb2;
    i2 = ni2;
}

// ---------------- pass 1: value-only scan (5 VALU/pair) — R13-validated ----
__global__ __launch_bounds__(TPB) void knn_scan_v(const float* __restrict__ coords,
                                                  float2* __restrict__ vals) {
    __shared__ float4 pts[CSZ];
    const int tid   = (int)threadIdx.x;
    const int tile  = blockIdx.x;
    const int chunk = blockIdx.y;
    const int b     = blockIdx.z;
    const float* basep = coords + (size_t)b * NPTS * 3;
    const int mbase = chunk * CSZ;

    if (tid < CSZ) {
        float x = basep[(mbase + tid) * 3 + 0];
        float y = basep[(mbase + tid) * 3 + 1];
        float z = basep[(mbase + tid) * 3 + 2];
        pts[tid] = make_float4(-2.0f * x, -2.0f * y, -2.0f * z, cand_w(x, y, z));
    }

    const int qbase = tile * (TPB * QF);
    float xn[QF], yn[QF], zn[QF], b1[QF], b2[QF];
#pragma unroll
    for (int q = 0; q < QF; ++q) {
        int n = qbase + q * TPB + tid;
        xn[q] = basep[n * 3 + 0];
        yn[q] = basep[n * 3 + 1];
        zn[q] = basep[n * 3 + 2];
        b1[q] = BIGD; b2[q] = BIGD;
    }
    __syncthreads();

    for (int p = 0; p < CSZ; p += 4) {
        float4 c[4];
#pragma unroll
        for (int j = 0; j < 4; ++j) c[j] = pts[p + j];
#pragma unroll
        for (int j = 0; j < 4; ++j) {
#pragma unroll
            for (int q = 0; q < QF; ++q) {
                float k = cand_key(c[j].x, c[j].y, c[j].z, c[j].w, xn[q], yn[q], zn[q]);
                b2[q] = fminf(fmaxf(k, b1[q]), b2[q]);   // med3 given b1<=b2
                b1[q] = fminf(k, b1[q]);
            }
        }
    }

#pragma unroll
    for (int q = 0; q < QF; ++q) {
        int n = qbase + q * TPB + tid;
        vals[(size_t)chunk * TOTQ + (size_t)b * NPTS + n] = make_float2(b1[q], b2[q]);
    }
}

// ---------------- pass 2: merge, re-scheduled for latency ----------------
// Block = 16 queries (same batch; 16 | 64 so c_self block-uniform). Grid 2048.
// Ph1: 16 subsets x 4 chunks/thread (8-lexup chains). Ph2: 16 threads reduce.
// Ph3: 4 waves x 4 queries each (vs R13's 16): cooperative rescan with all
// three chunk loads hoisted ahead of the dependent lexup/butterfly chain.
__global__ __launch_bounds__(TPB) void knn_merge_w(const float* __restrict__ coords,
                                                   const float2* __restrict__ vals,
                                                   float* __restrict__ out) {
    __shared__ float4 part[16][QPB];
    __shared__ int4 rl[QPB];
    __shared__ int2 res[QPB];
    const int t  = (int)threadIdx.x;
    const int qb = blockIdx.x * QPB;           // global query base
    const int b  = qb >> 12;
    const int c_self = (qb & (NPTS - 1)) >> 6; // block-uniform
    const float* bp = coords + (size_t)b * NPTS * 3;

    // Phase 1: thread (s = t>>4, qi = t&15) merges chunks s*4..s*4+3 of query qi.
    {
        const int s  = t >> 4;
        const int qi = t & 15;
        const int q  = qb + qi;
        float f1 = BIGD, f2 = BIGD;
        int t1 = MAXI, t2 = MAXI;
#pragma unroll
        for (int u = 0; u < 4; ++u) {
            const int c = s * 4 + u;
            if (c == c_self) continue;
            float2 v = vals[(size_t)c * TOTQ + q];
            lexup(v.x, 2 * c + 0, f1, t1, f2, t2);
            lexup(v.y, 2 * c + 1, f1, t1, f2, t2);
        }
        part[s][qi] = make_float4(f1, __int_as_float(t1), f2, __int_as_float(t2));
    }
    __syncthreads();

    // Phase 2: 16 threads combine subsets, build sorted rescan set.
    if (t < QPB) {
        float f1 = BIGD, f2 = BIGD;
        int t1 = MAXI, t2 = MAXI;
#pragma unroll
        for (int ss = 0; ss < 16; ++ss) {
            float4 p = part[ss][t];
            lexup(p.x, __float_as_int(p.y), f1, t1, f2, t2);
            lexup(p.z, __float_as_int(p.w), f1, t1, f2, t2);
        }
        const int ca = t1 >> 1;
        const int cb = t2 >> 1;
        const int lo = min(min(ca, cb), c_self);
        const int hi = max(max(ca, cb), c_self);
        const int md = ca + cb + c_self - lo - hi;
        rl[t] = make_int4(lo, md, hi, 0);
    }
    __syncthreads();

    // Phase 3: wave w handles queries w*4..w*4+3; 64 lanes cooperate per query.
    {
        const int lane = t & 63;
        const int w = t >> 6;
        for (int j = 0; j < 4; ++j) {
            const int qj = w * 4 + j;
            const int4 r = rl[qj];             // LDS broadcast
            const int n = (qb + qj) & (NPTS - 1);
            const float xq = bp[n * 3 + 0];    // wave-uniform broadcast loads
            const float yq = bp[n * 3 + 1];
            const float zq = bp[n * 3 + 2];

            // Hoist all three chunks' candidate coords (dups harmless for loads).
            const int m0 = r.x * CSZ + lane;
            const int m1 = r.y * CSZ + lane;
            const int m2 = r.z * CSZ + lane;
            float cx0 = bp[m0 * 3 + 0], cy0 = bp[m0 * 3 + 1], cz0 = bp[m0 * 3 + 2];
            float cx1 = bp[m1 * 3 + 0], cy1 = bp[m1 * 3 + 1], cz1 = bp[m1 * 3 + 2];
            float cx2 = bp[m2 * 3 + 0], cy2 = bp[m2 * 3 + 1], cz2 = bp[m2 * 3 + 2];

            float b1 = BIGD, b2 = BIGD;
            int i1 = MAXI, i2 = MAXI;
            // u=0 always; u=1 iff r.y!=r.x; u=2 iff r.z!=r.y (sorted, dedup —
            // duplicate feeds would corrupt lexicographic top-2).
            {
                float k = cand_key(-2.0f * cx0, -2.0f * cy0, -2.0f * cz0,
                                   cand_w(cx0, cy0, cz0), xq, yq, zq);
                const bool self = (m0 == n);
                lexup(self ? BIGD : k, self ? MAXI : m0, b1, i1, b2, i2);
            }
            if (r.y != r.x) {
                float k = cand_key(-2.0f * cx1, -2.0f * cy1, -2.0f * cz1,
                                   cand_w(cx1, cy1, cz1), xq, yq, zq);
                const bool self = (m1 == n);
                lexup(self ? BIGD : k, self ? MAXI : m1, b1, i1, b2, i2);
            }
            if (r.z != r.y) {
                float k = cand_key(-2.0f * cx2, -2.0f * cy2, -2.0f * cz2,
                                   cand_w(cx2, cy2, cz2), xq, yq, zq);
                const bool self = (m2 == n);
                lexup(self ? BIGD : k, self ? MAXI : m2, b1, i1, b2, i2);
            }
            // 64-lane lexicographic butterfly top-2.
#pragma unroll
            for (int off = 1; off < 64; off <<= 1) {
                const float ok1 = __shfl_xor(b1, off);
                const int   oi1 = __shfl_xor(i1, off);
                const float ok2 = __shfl_xor(b2, off);
                const int   oi2 = __shfl_xor(i2, off);
                lexup(ok1, oi1, b1, i1, b2, i2);
                lexup(ok2, oi2, b1, i1, b2, i2);
            }
            if (lane == 0) res[qj] = make_int2(i1, i2);
        }
    }
    __syncthreads();

    // Phase 4: epilogue spread over 48 threads (A/C) + 16 (indices).
    if (t < 48) {
        const int qj = t / 3;
        const int d  = t % 3;
        const int q  = qb + qj;
        const int i1 = res[qj].x;
        const int i2 = res[qj].y;
        float* A = out;
        float* C = out + (size_t)TOTQ * 3;
        A[(size_t)q * 3 + d] = bp[i1 * 3 + d];
        C[(size_t)q * 3 + d] = bp[i2 * 3 + d];
    }
    if (t < QPB) {
        const int q = qb + t;
        float* I1 = out + (size_t)2 * TOTQ * 3;
        float* I2 = I1 + (size_t)TOTQ;
        I1[q] = (float)res[t].x;
        I2[q] = (float)res[t].y;
    }
}

// ---------------- fallback (tiny ws): monolithic brute force ----------------
__device__ __forceinline__ void top2min(float k, int m,
                                        float& b1, int& i1,
                                        float& b2, int& i2) {
    bool c1 = k < b1;
    bool c2 = k < b2;
    int ni2 = c2 ? m : i2;
    i2 = c1 ? i1 : ni2;
    i1 = c1 ? m : i1;
    b2 = fminf(fmaxf(k, b1), b2);
    b1 = fminf(k, b1);
}

__global__ __launch_bounds__(TPB) void knn_full(const float* __restrict__ coords,
                                                float* __restrict__ out) {
    __shared__ float4 pts[NPTS];  // 64 KB
    const int tid  = (int)threadIdx.x;
    const int tile = blockIdx.x;
    const int b    = blockIdx.y;
    const float* basep = coords + (size_t)b * NPTS * 3;

    for (int p = tid; p < NPTS; p += TPB) {
        float x = basep[p * 3 + 0];
        float y = basep[p * 3 + 1];
        float z = basep[p * 3 + 2];
        pts[p] = make_float4(-2.0f * x, -2.0f * y, -2.0f * z, cand_w(x, y, z));
    }
    const int n = tile * TPB + tid;
    const float xn = basep[n * 3 + 0];
    const float yn = basep[n * 3 + 1];
    const float zn = basep[n * 3 + 2];
    __syncthreads();

    float b1 = BIGD, b2 = BIGD;
    int i1 = 0, i2 = 0;
    for (int p = 0; p < NPTS; p += 4) {
#pragma unroll
        for (int j = 0; j < 4; ++j) {
            float4 c = pts[p + j];
            float k = cand_key(c.x, c.y, c.z, c.w, xn, yn, zn);
            k = (p + j == n) ? BIGD : k;
            top2min(k, p + j, b1, i1, b2, i2);
        }
    }

    const int q = b * NPTS + n;
    float* A  = out;
    float* C  = out + (size_t)TOTQ * 3;
    float* I1 = out + (size_t)2 * TOTQ * 3;
    float* I2 = I1 + (size_t)TOTQ;
    float4 p1 = pts[i1];
    float4 p2 = pts[i2];
    A[(size_t)q * 3 + 0] = -0.5f * p1.x;
    A[(size_t)q * 3 + 1] = -0.5f * p1.y;
    A[(size_t)q * 3 + 2] = -0.5f * p1.z;
    C[(size_t)q * 3 + 0] = -0.5f * p2.x;
    C[(size_t)q * 3 + 1] = -0.5f * p2.y;
    C[(size_t)q * 3 + 2] = -0.5f * p2.z;
    I1[q] = (float)i1;
    I2[q] = (float)i2;
}

extern "C" void kernel_launch(void* const* d_in, const int* in_sizes, int n_in,
                              void* d_out, int out_size, void* d_ws, size_t ws_size,
                              hipStream_t stream) {
    const float* coords = (const float*)d_in[0];
    float* out = (float*)d_out;

    const size_t need = (size_t)NCH * TOTQ * sizeof(float2);   // 16 MB
    if (ws_size >= need) {
        float2* vals = (float2*)d_ws;
        hipLaunchKernelGGL(knn_scan_v, dim3(NPTS / (TPB * QF), NCH, BATCH), dim3(TPB),
                           0, stream, coords, vals);
        hipLaunchKernelGGL(knn_merge_w, dim3(TOTQ / QPB), dim3(TPB), 0, stream,
                           coords, vals, out);
    } else {
        hipLaunchKernelGGL(knn_full, dim3(NPTS / TPB, BATCH), dim3(TPB), 0, stream,
                           coords, out);
    }
}